// Round 1
// baseline (703.530 us; speedup 1.0000x reference)
//
#include <hip/hip_runtime.h>

#define K_NB 16
#define NB 4
#define BLK 512

__device__ __forceinline__ float f4_get(const float4& v, int ii) {
    return ii == 0 ? v.x : (ii == 1 ? v.y : (ii == 2 ? v.z : v.w));
}

// ws <- [5][128][128]: W0c=Ws0@P0, Wdc=Wrd@P0, W1c=Ws1@P1, Wrc=Wrv0@P1, W2c=Ws2@P2
__global__ void combine_weights_kernel(
    const float* __restrict__ tp_w_same,   // [3][128][128]
    const float* __restrict__ tp_w_rv0,    // [128][128]
    const float* __restrict__ tp_w_rdot,   // [128][128]
    const float* __restrict__ proj_w,      // [3][128][128]
    float* __restrict__ wc)                // [5][128][128]
{
    const int b = blockIdx.x;
    const int m = b >> 6;                          // matrix 0..4
    const int rr = ((b & 63) << 1) + (threadIdx.x >> 7);   // row 0..127
    const int d = threadIdx.x & 127;
    const float* A;
    const float* B;
    if (m == 0)      { A = tp_w_same;         B = proj_w; }
    else if (m == 1) { A = tp_w_rdot;         B = proj_w; }
    else if (m == 2) { A = tp_w_same + 16384; B = proj_w + 16384; }
    else if (m == 3) { A = tp_w_rv0;          B = proj_w + 16384; }
    else             { A = tp_w_same + 32768; B = proj_w + 32768; }
    float acc = 0.0f;
    #pragma unroll 4
    for (int c = 0; c < 128; ++c)
        acc = fmaf(A[rr * 128 + c], B[c * 128 + d], acc);
    wc[(m * 128 + rr) * 128 + d] = acc;
}

__global__ __launch_bounds__(BLK, 4) void foa_main_kernel(
    const float* __restrict__ alpha,        // [N][K][8]
    const float* __restrict__ value,        // [N][9][128]
    const float* __restrict__ x_edge,       // [N][K][64]
    const float* __restrict__ node_pos,     // [N][3]
    const float* __restrict__ edge_dis,     // [N][K]
    const float* __restrict__ exp_node_pos, // [M][3]
    const float* __restrict__ rad_w1,       // [64][128]
    const float* __restrict__ rad_b1,       // [128]
    const float* __restrict__ ln_g,         // [128]
    const float* __restrict__ ln_b,         // [128]
    const float* __restrict__ rad_w2,       // [128][128]
    const float* __restrict__ rad_b2,       // [128]
    const float* __restrict__ proj_b,       // [128]
    const float* __restrict__ wc,           // [5][128][128] combined
    const int* __restrict__ outcell_index,  // [M]
    const int* __restrict__ f_sparse_idx,   // [N][K]
    float* __restrict__ out)                // [N][9][128]
{
    __shared__ float xe[64][64];          // 16 KB  x_edge tile
    __shared__ float hbuf[64][128];       // 32 KB  h, then reused for a
    __shared__ float tpin[NB][13][128];   // 26 KB  aV[0..8], arV0[0..2], ardot
    __shared__ float rE[64][3];
    __shared__ float alphaE[64][8];
    __shared__ float invdE[64];
    __shared__ int gidxE[64];

    const int t = threadIdx.x;
    const int n0 = blockIdx.x * NB;

    // ---------------- phase 0: per-edge metadata ----------------
    if (t < 64) {
        const int nn = n0 + (t >> 4);
        const int k = t & 15;
        const int eidx = f_sparse_idx[nn * K_NB + k];
        gidxE[t] = outcell_index[eidx];
        rE[t][0] = node_pos[nn * 3 + 0] - exp_node_pos[eidx * 3 + 0];
        rE[t][1] = node_pos[nn * 3 + 1] - exp_node_pos[eidx * 3 + 1];
        rE[t][2] = node_pos[nn * 3 + 2] - exp_node_pos[eidx * 3 + 2];
        invdE[t] = 1.0f / (edge_dis[nn * K_NB + k] + 1e-8f);
    }
    {
        const int e = t >> 3, hh = t & 7;
        const int nn = n0 + (e >> 4), k = e & 15;
        alphaE[e][hh] = alpha[(nn * K_NB + k) * 8 + hh];
    }
    {
        const float4* src4 = reinterpret_cast<const float4*>(x_edge + (size_t)n0 * K_NB * 64);
        float4* dst4 = reinterpret_cast<float4*>(&xe[0][0]);
        dst4[t] = src4[t];
        dst4[t + BLK] = src4[t + BLK];
    }
    __syncthreads();

    const int jh = t & 63;          // column pair (jh, jh+64)
    const int g = t >> 6;           // wave id -> edge group
    const int ebase = g << 3;       // 8 edges per wave

    // ---------------- phase 2: GEMM1 [8,64]@[64,128] + LN + SiLU -> hbuf ----
    {
        float acc0[8], acc1[8];
        #pragma unroll
        for (int e = 0; e < 8; ++e) { acc0[e] = 0.0f; acc1[e] = 0.0f; }
        for (int i = 0; i < 64; i += 4) {
            float4 xv[8];
            #pragma unroll
            for (int e = 0; e < 8; ++e)
                xv[e] = *reinterpret_cast<const float4*>(&xe[ebase + e][i]);
            #pragma unroll
            for (int ii = 0; ii < 4; ++ii) {
                const float w0 = rad_w1[(i + ii) * 128 + jh];
                const float w1 = rad_w1[(i + ii) * 128 + jh + 64];
                #pragma unroll
                for (int e = 0; e < 8; ++e) {
                    const float x = f4_get(xv[e], ii);
                    acc0[e] = fmaf(x, w0, acc0[e]);
                    acc1[e] = fmaf(x, w1, acc1[e]);
                }
            }
        }
        const float b1a = rad_b1[jh], b1b = rad_b1[jh + 64];
        const float ga = ln_g[jh], gb = ln_g[jh + 64];
        const float ba = ln_b[jh], bb = ln_b[jh + 64];
        #pragma unroll
        for (int e = 0; e < 8; ++e) {
            const float v0 = acc0[e] + b1a;
            const float v1 = acc1[e] + b1b;
            float s = v0 + v1;
            float s2 = v0 * v0 + v1 * v1;
            #pragma unroll
            for (int off = 32; off > 0; off >>= 1) {
                s  += __shfl_xor(s, off, 64);
                s2 += __shfl_xor(s2, off, 64);
            }
            const float mu = s * (1.0f / 128.0f);
            const float var = s2 * (1.0f / 128.0f) - mu * mu;
            const float rstd = rsqrtf(var + 1e-5f);
            float h0 = (v0 - mu) * rstd * ga + ba;
            float h1 = (v1 - mu) * rstd * gb + bb;
            h0 = h0 / (1.0f + __expf(-h0));
            h1 = h1 / (1.0f + __expf(-h1));
            hbuf[ebase + e][jh] = h0;
            hbuf[ebase + e][jh + 64] = h1;
        }
    }
    __syncthreads();

    // ---------------- phase 3: GEMM2 [8,128]@[128,128] -> a (reuse hbuf) ----
    {
        float acc0[8], acc1[8];
        #pragma unroll
        for (int e = 0; e < 8; ++e) { acc0[e] = 0.0f; acc1[e] = 0.0f; }
        for (int i = 0; i < 128; i += 4) {
            float4 hv[8];
            #pragma unroll
            for (int e = 0; e < 8; ++e)
                hv[e] = *reinterpret_cast<const float4*>(&hbuf[ebase + e][i]);
            #pragma unroll
            for (int ii = 0; ii < 4; ++ii) {
                const float w0 = rad_w2[(i + ii) * 128 + jh];
                const float w1 = rad_w2[(i + ii) * 128 + jh + 64];
                #pragma unroll
                for (int e = 0; e < 8; ++e) {
                    const float x = f4_get(hv[e], ii);
                    acc0[e] = fmaf(x, w0, acc0[e]);
                    acc1[e] = fmaf(x, w1, acc1[e]);
                }
            }
        }
        const float b2a = rad_b2[jh], b2b = rad_b2[jh + 64];
        const int hd0 = jh >> 4;
        float av0[8], av1[8];
        #pragma unroll
        for (int e = 0; e < 8; ++e) {
            const float id = invdE[ebase + e];
            av0[e] = alphaE[ebase + e][hd0]     * (acc0[e] + b2a) * id;
            av1[e] = alphaE[ebase + e][hd0 + 4] * (acc1[e] + b2b) * id;
        }
        __syncthreads();   // all reads of h done before overwrite
        #pragma unroll
        for (int e = 0; e < 8; ++e) {
            hbuf[ebase + e][jh]      = av0[e];
            hbuf[ebase + e][jh + 64] = av1[e];
        }
    }
    __syncthreads();

    // ---------------- phase 4: gather value rows + TP accumulate ----------
    {
        const int c = t & 127;
        const int nodeg = t >> 7;      // node within block
        const int eb = nodeg << 4;     // 16 edges
        float aV[9];
        #pragma unroll
        for (int l = 0; l < 9; ++l) aV[l] = 0.0f;
        float ar0 = 0.0f, ar1 = 0.0f, ar2 = 0.0f, ardot = 0.0f;
        #pragma unroll 2
        for (int k = 0; k < 16; ++k) {
            const int e = eb + k;
            const float* vp = value + gidxE[e] * 1152 + c;
            const float av = hbuf[e][c];
            float v[9];
            #pragma unroll
            for (int l = 0; l < 9; ++l) v[l] = vp[l * 128];
            #pragma unroll
            for (int l = 0; l < 9; ++l) aV[l] = fmaf(av, v[l], aV[l]);
            const float w0 = av * v[0];
            const float r0 = rE[e][0], r1 = rE[e][1], r2 = rE[e][2];
            ar0 = fmaf(r0, w0, ar0);
            ar1 = fmaf(r1, w0, ar1);
            ar2 = fmaf(r2, w0, ar2);
            ardot = fmaf(av, fmaf(r0, v[1], fmaf(r1, v[2], r2 * v[3])), ardot);
        }
        #pragma unroll
        for (int l = 0; l < 9; ++l) tpin[nodeg][l][c] = aV[l];
        tpin[nodeg][9][c]  = ar0;
        tpin[nodeg][10][c] = ar1;
        tpin[nodeg][11][c] = ar2;
        tpin[nodeg][12][c] = ardot;
    }
    __syncthreads();

    // ---------------- phase 5: 13 GEMV-rows through combined weights ------
    {
        const int d = t & 127;
        const int nodeg = t >> 7;
        float y[9];
        #pragma unroll
        for (int l = 0; l < 9; ++l) y[l] = 0.0f;

        // pass A: rows 0..6 (aV)
        for (int c = 0; c < 128; c += 4) {
            float4 tv[7];
            #pragma unroll
            for (int r = 0; r < 7; ++r)
                tv[r] = *reinterpret_cast<const float4*>(&tpin[nodeg][r][c]);
            #pragma unroll
            for (int ii = 0; ii < 4; ++ii) {
                const int cc = c + ii;
                const float w0 = wc[0 * 16384 + cc * 128 + d];
                const float w1 = wc[2 * 16384 + cc * 128 + d];
                const float w2 = wc[4 * 16384 + cc * 128 + d];
                y[0] = fmaf(f4_get(tv[0], ii), w0, y[0]);
                y[1] = fmaf(f4_get(tv[1], ii), w1, y[1]);
                y[2] = fmaf(f4_get(tv[2], ii), w1, y[2]);
                y[3] = fmaf(f4_get(tv[3], ii), w1, y[3]);
                y[4] = fmaf(f4_get(tv[4], ii), w2, y[4]);
                y[5] = fmaf(f4_get(tv[5], ii), w2, y[5]);
                y[6] = fmaf(f4_get(tv[6], ii), w2, y[6]);
            }
        }
        // pass B: rows 7,8 (aV->W2c), 9..11 (arV0->Wrc), 12 (ardot->Wdc)
        for (int c = 0; c < 128; c += 4) {
            float4 tv[6];
            #pragma unroll
            for (int r = 0; r < 6; ++r)
                tv[r] = *reinterpret_cast<const float4*>(&tpin[nodeg][7 + r][c]);
            #pragma unroll
            for (int ii = 0; ii < 4; ++ii) {
                const int cc = c + ii;
                const float w2 = wc[4 * 16384 + cc * 128 + d];
                const float wr = wc[3 * 16384 + cc * 128 + d];
                const float wd = wc[1 * 16384 + cc * 128 + d];
                y[7] = fmaf(f4_get(tv[0], ii), w2, y[7]);
                y[8] = fmaf(f4_get(tv[1], ii), w2, y[8]);
                y[1] = fmaf(f4_get(tv[2], ii), wr, y[1]);
                y[2] = fmaf(f4_get(tv[3], ii), wr, y[2]);
                y[3] = fmaf(f4_get(tv[4], ii), wr, y[3]);
                y[0] = fmaf(f4_get(tv[5], ii), wd, y[0]);
            }
        }
        y[0] += proj_b[d];
        float* op = out + (size_t)(n0 + nodeg) * 1152 + d;
        #pragma unroll
        for (int l = 0; l < 9; ++l) op[l * 128] = y[l];
    }
}

extern "C" void kernel_launch(void* const* d_in, const int* in_sizes, int n_in,
                              void* d_out, int out_size, void* d_ws, size_t ws_size,
                              hipStream_t stream)
{
    const float* alpha        = (const float*)d_in[0];
    const float* value        = (const float*)d_in[1];
    const float* x_edge       = (const float*)d_in[2];
    const float* node_pos     = (const float*)d_in[3];
    const float* edge_dis     = (const float*)d_in[4];
    const float* exp_node_pos = (const float*)d_in[5];
    const float* rad_w1       = (const float*)d_in[6];
    const float* rad_b1       = (const float*)d_in[7];
    const float* ln_g         = (const float*)d_in[8];
    const float* ln_b         = (const float*)d_in[9];
    const float* rad_w2       = (const float*)d_in[10];
    const float* rad_b2       = (const float*)d_in[11];
    const float* tp_w_same    = (const float*)d_in[12];
    const float* tp_w_rv0     = (const float*)d_in[13];
    const float* tp_w_rdot    = (const float*)d_in[14];
    const float* proj_w       = (const float*)d_in[15];
    const float* proj_b       = (const float*)d_in[16];
    const int* outcell_index  = (const int*)d_in[17];
    const int* f_sparse_idx   = (const int*)d_in[18];
    float* out = (float*)d_out;
    float* wc  = (float*)d_ws;   // 5*128*128 floats = 320 KB

    const int N = in_sizes[0] / (K_NB * 8);   // 16000

    combine_weights_kernel<<<320, 256, 0, stream>>>(tp_w_same, tp_w_rv0, tp_w_rdot, proj_w, wc);
    foa_main_kernel<<<N / NB, BLK, 0, stream>>>(alpha, value, x_edge, node_pos, edge_dis,
                                                exp_node_pos, rad_w1, rad_b1, ln_g, ln_b,
                                                rad_w2, rad_b2, proj_b, wc,
                                                outcell_index, f_sparse_idx, out);
}

// Round 2
// 262.676 us; speedup vs baseline: 2.6783x; 2.6783x over previous
//
#include <hip/hip_runtime.h>

typedef __attribute__((ext_vector_type(8))) short bh8;
typedef __attribute__((ext_vector_type(4))) float fv4;

#define NB 8
#define EB 128
#define BLK 512

#define MFMA(a, b, c) __builtin_amdgcn_mfma_f32_16x16x32_bf16((a), (b), (c), 0, 0, 0)

__device__ __forceinline__ unsigned short f2bf(float x) {
    unsigned int u = __float_as_uint(x);
    u += 0x7fffu + ((u >> 16) & 1u);
    return (unsigned short)(u >> 16);
}
__device__ __forceinline__ float bf2f(unsigned short h) {
    return __uint_as_float(((unsigned int)h) << 16);
}
// element index into a row-major [*][128] bf16 LDS tile, 8-elem XOR swizzle
__device__ __forceinline__ int swz(int row, int col) {
    return row * 128 + ((((col >> 3) ^ (row & 7)) << 3) | (col & 7));
}

// ws layout (ushort): [0,8192) w1T[128][64]; [8192,24576) w2T[128][128];
// [24576,106496) wcT[5][128][128]  (wcT[m][d][c] = combined_m[c][d], bf16)
__global__ void prep_kernel(
    const float* __restrict__ rad_w1, const float* __restrict__ rad_w2,
    const float* __restrict__ tp_w_same, const float* __restrict__ tp_w_rv0,
    const float* __restrict__ tp_w_rdot, const float* __restrict__ proj_w,
    unsigned short* __restrict__ ws)
{
    unsigned short* w1T = ws;
    unsigned short* w2T = ws + 8192;
    unsigned short* wcT = ws + 24576;
    const int b = blockIdx.x, t = threadIdx.x;
    if (b < 640) {
        const int m = b >> 7, d = b & 127;
        const float* A; const float* B;
        if (m == 0)      { A = tp_w_same;         B = proj_w; }
        else if (m == 1) { A = tp_w_rdot;         B = proj_w; }
        else if (m == 2) { A = tp_w_same + 16384; B = proj_w + 16384; }
        else if (m == 3) { A = tp_w_rv0;          B = proj_w + 16384; }
        else             { A = tp_w_same + 32768; B = proj_w + 32768; }
        __shared__ float Bs[128];
        Bs[t] = B[t * 128 + d];
        __syncthreads();
        float acc = 0.f;
        const float* Ar = A + t * 128;
        #pragma unroll 4
        for (int x = 0; x < 128; ++x) acc = fmaf(Ar[x], Bs[x], acc);
        wcT[m * 16384 + d * 128 + t] = f2bf(acc);
    } else {
        const int bb = b - 640;
        #pragma unroll
        for (int i = 0; i < 12; ++i) {
            const int idx = bb * 1536 + i * 128 + t;
            if (idx < 8192) {
                const int j = idx >> 6, c = idx & 63;
                w1T[idx] = f2bf(rad_w1[c * 128 + j]);
            } else if (idx < 24576) {
                const int i2 = idx - 8192;
                const int j = i2 >> 7, c = i2 & 127;
                w2T[i2] = f2bf(rad_w2[c * 128 + j]);
            }
        }
    }
}

__global__ __launch_bounds__(BLK, 4) void foa_main(
    const float* __restrict__ alpha,        // [N*K*8]
    const float* __restrict__ value,        // [N][9][128]
    const float* __restrict__ x_edge,       // [N*K][64]
    const float* __restrict__ node_pos,     // [N][3]
    const float* __restrict__ edge_dis,     // [N*K]
    const float* __restrict__ exp_node_pos, // [M][3]
    const float* __restrict__ rad_b1, const float* __restrict__ ln_g,
    const float* __restrict__ ln_b, const float* __restrict__ rad_b2,
    const float* __restrict__ proj_b,
    const unsigned short* __restrict__ ws,
    const int* __restrict__ outcell_index,
    const int* __restrict__ f_sparse_idx,
    float* __restrict__ out)                // [N][9][128]
{
    // tpin (144 rows, 36 KB) aliases hbuf (128 rows): hbuf dead before tpin born
    __shared__ __align__(16) unsigned short s_un[18432];
    __shared__ __align__(16) unsigned short s_abuf[16384];
    __shared__ float s_alpha[1024];
    __shared__ float s_rE[EB][3];
    __shared__ float s_invd[EB];
    __shared__ int   s_gidx[EB];

    const unsigned short* w1T = ws;
    const unsigned short* w2T = ws + 8192;
    const unsigned short* wcT = ws + 24576;

    const int t = threadIdx.x;
    const int e0 = blockIdx.x * EB;
    const int n0 = blockIdx.x * NB;
    const int lane = t & 63, w = t >> 6;
    const int ln15 = lane & 15, lq = lane >> 4;

    // ---------- phase 0: per-edge metadata ----------
    if (t < EB) {
        const int eidx = f_sparse_idx[e0 + t];
        s_gidx[t] = outcell_index[eidx];
        const int nn = n0 + (t >> 4);
        s_rE[t][0] = node_pos[nn * 3 + 0] - exp_node_pos[(size_t)eidx * 3 + 0];
        s_rE[t][1] = node_pos[nn * 3 + 1] - exp_node_pos[(size_t)eidx * 3 + 1];
        s_rE[t][2] = node_pos[nn * 3 + 2] - exp_node_pos[(size_t)eidx * 3 + 2];
        s_invd[t] = 1.0f / (edge_dis[e0 + t] + 1e-8f);
    }
    s_alpha[t]       = alpha[(size_t)e0 * 8 + t];
    s_alpha[t + 512] = alpha[(size_t)e0 * 8 + 512 + t];

    unsigned short* hbuf = s_un;

    // ---------- phase 2: GEMM1 [128,64]@w1 -> LN -> SiLU -> hbuf (bf16) ----
    {
        bh8 af0, af1;
        {
            const float* xp = x_edge + ((size_t)(e0 + 16 * w + ln15)) * 64 + lq * 8;
            const float4 u0 = *(const float4*)(xp);
            const float4 u1 = *(const float4*)(xp + 4);
            const float4 u2 = *(const float4*)(xp + 32);
            const float4 u3 = *(const float4*)(xp + 36);
            af0[0] = (short)f2bf(u0.x); af0[1] = (short)f2bf(u0.y);
            af0[2] = (short)f2bf(u0.z); af0[3] = (short)f2bf(u0.w);
            af0[4] = (short)f2bf(u1.x); af0[5] = (short)f2bf(u1.y);
            af0[6] = (short)f2bf(u1.z); af0[7] = (short)f2bf(u1.w);
            af1[0] = (short)f2bf(u2.x); af1[1] = (short)f2bf(u2.y);
            af1[2] = (short)f2bf(u2.z); af1[3] = (short)f2bf(u2.w);
            af1[4] = (short)f2bf(u3.x); af1[5] = (short)f2bf(u3.y);
            af1[6] = (short)f2bf(u3.z); af1[7] = (short)f2bf(u3.w);
        }
        fv4 acc1[8];
        #pragma unroll
        for (int ct = 0; ct < 8; ++ct) { fv4 z = {0.f, 0.f, 0.f, 0.f}; acc1[ct] = z; }
        #pragma unroll
        for (int ct = 0; ct < 8; ++ct) {
            const bh8* bp = (const bh8*)&w1T[(16 * ct + ln15) * 64 + lq * 8];
            acc1[ct] = MFMA(af0, bp[0], acc1[ct]);
            acc1[ct] = MFMA(af1, bp[4], acc1[ct]);   // +32 elems = second k-tile
        }
        float b1v[8], gv[8], bvv[8];
        #pragma unroll
        for (int ct = 0; ct < 8; ++ct) {
            b1v[ct] = rad_b1[16 * ct + ln15];
            gv[ct]  = ln_g[16 * ct + ln15];
            bvv[ct] = ln_b[16 * ct + ln15];
        }
        #pragma unroll
        for (int r = 0; r < 4; ++r) {
            float vv[8], s = 0.f, s2 = 0.f;
            #pragma unroll
            for (int ct = 0; ct < 8; ++ct) {
                const float x = acc1[ct][r] + b1v[ct];
                vv[ct] = x; s += x; s2 += x * x;
            }
            s += __shfl_xor(s, 1);  s2 += __shfl_xor(s2, 1);
            s += __shfl_xor(s, 2);  s2 += __shfl_xor(s2, 2);
            s += __shfl_xor(s, 4);  s2 += __shfl_xor(s2, 4);
            s += __shfl_xor(s, 8);  s2 += __shfl_xor(s2, 8);
            const float mu = s * 0.0078125f;
            const float var = s2 * 0.0078125f - mu * mu;
            const float rstd = rsqrtf(var + 1e-5f);
            const int rowg = 16 * w + lq * 4 + r;
            #pragma unroll
            for (int ct = 0; ct < 8; ++ct) {
                float hh = (vv[ct] - mu) * rstd * gv[ct] + bvv[ct];
                hh = hh / (1.f + __expf(-hh));
                hbuf[swz(rowg, 16 * ct + ln15)] = f2bf(hh);
            }
        }
    }
    __syncthreads();

    // ---------- phase 3: GEMM2 [128,128]@w2 -> a -> s_abuf (bf16) ----------
    {
        fv4 acc2[8];
        #pragma unroll
        for (int ct = 0; ct < 8; ++ct) { fv4 z = {0.f, 0.f, 0.f, 0.f}; acc2[ct] = z; }
        #pragma unroll
        for (int ks = 0; ks < 4; ++ks) {
            const int arow = 16 * w + ln15;
            const int acb = (lq + 4 * ks) ^ (arow & 7);
            const bh8 a = *(const bh8*)&hbuf[arow * 128 + (acb << 3)];
            #pragma unroll
            for (int ct = 0; ct < 8; ++ct) {
                const bh8 b = *(const bh8*)&w2T[(16 * ct + ln15) * 128 + lq * 8 + 32 * ks];
                acc2[ct] = MFMA(a, b, acc2[ct]);
            }
        }
        #pragma unroll
        for (int ct = 0; ct < 8; ++ct) {
            const float b2 = rad_b2[16 * ct + ln15];
            #pragma unroll
            for (int r = 0; r < 4; ++r) {
                const int e = 16 * w + lq * 4 + r;
                const float aval = s_alpha[e * 8 + ct] * (acc2[ct][r] + b2) * s_invd[e];
                s_abuf[swz(e, 16 * ct + ln15)] = f2bf(aval);
            }
        }
    }
    __syncthreads();

    // ---------- phase 4: gather V, TP accumulate -> tpin (bf16, 144 rows) --
    // row map: [0,8) aV0 | [16,24) ardot | 32+(l-1)*8+nn l=1..3 | 64+x*8+nn |
    //          96+(l-4)*8+nn l=4..8 ; pad rows zeroed
    unsigned short* tpin = s_un;
    {
        const int padrows[5] = {8, 24, 56, 88, 136};
        #pragma unroll
        for (int g = 0; g < 5; ++g) {
            unsigned int* pz = (unsigned int*)&tpin[padrows[g] * 128];
            pz[t] = 0u;   // 8 rows * 128 bf16 = 512 uints, one per thread
        }
    }
    {
        const int c = t & 127;
        const int ng = t >> 7;
        #pragma unroll
        for (int hh = 0; hh < 2; ++hh) {
            const int nn = 2 * ng + hh;
            float aV0 = 0.f, aV1 = 0.f, aV2 = 0.f, aV3 = 0.f, aV4 = 0.f;
            float aV5 = 0.f, aV6 = 0.f, aV7 = 0.f, aV8 = 0.f;
            float ar0 = 0.f, ar1 = 0.f, ar2 = 0.f, ard = 0.f;
            #pragma unroll 4
            for (int k = 0; k < 16; ++k) {
                const int e = nn * 16 + k;
                const float av = bf2f(s_abuf[swz(e, c)]);
                const float* vp = value + (size_t)s_gidx[e] * 1152 + c;
                const float v0 = vp[0],    v1 = vp[128],  v2 = vp[256];
                const float v3 = vp[384],  v4 = vp[512],  v5 = vp[640];
                const float v6 = vp[768],  v7 = vp[896],  v8 = vp[1024];
                aV0 = fmaf(av, v0, aV0); aV1 = fmaf(av, v1, aV1);
                aV2 = fmaf(av, v2, aV2); aV3 = fmaf(av, v3, aV3);
                aV4 = fmaf(av, v4, aV4); aV5 = fmaf(av, v5, aV5);
                aV6 = fmaf(av, v6, aV6); aV7 = fmaf(av, v7, aV7);
                aV8 = fmaf(av, v8, aV8);
                const float r0 = s_rE[e][0], r1 = s_rE[e][1], r2 = s_rE[e][2];
                const float w0 = av * v0;
                ar0 = fmaf(r0, w0, ar0);
                ar1 = fmaf(r1, w0, ar1);
                ar2 = fmaf(r2, w0, ar2);
                ard = fmaf(av, fmaf(r0, v1, fmaf(r1, v2, r2 * v3)), ard);
            }
            tpin[swz(nn, c)]       = f2bf(aV0);
            tpin[swz(16 + nn, c)]  = f2bf(ard);
            tpin[swz(32 + nn, c)]  = f2bf(aV1);
            tpin[swz(40 + nn, c)]  = f2bf(aV2);
            tpin[swz(48 + nn, c)]  = f2bf(aV3);
            tpin[swz(64 + nn, c)]  = f2bf(ar0);
            tpin[swz(72 + nn, c)]  = f2bf(ar1);
            tpin[swz(80 + nn, c)]  = f2bf(ar2);
            tpin[swz(96 + nn, c)]  = f2bf(aV4);
            tpin[swz(104 + nn, c)] = f2bf(aV5);
            tpin[swz(112 + nn, c)] = f2bf(aV6);
            tpin[swz(120 + nn, c)] = f2bf(aV7);
            tpin[swz(128 + nn, c)] = f2bf(aV8);
        }
    }
    __syncthreads();

    // ---------- phase 5: MFMA projection through combined weights ----------
    // wave w = col-tile (16 output dims). 9 A-tiles, 6 accumulators
    {
        fv4 accA, accB0, accB1, accC0, accC1, accC2;
        { fv4 z = {0.f,0.f,0.f,0.f}; accA=z; accB0=z; accB1=z; accC0=z; accC1=z; accC2=z; }
        #pragma unroll
        for (int ks = 0; ks < 4; ++ks) {
            const int cb = lq + 4 * ks;
        #define LDA(tb) (*(const bh8*)&tpin[((tb) + ln15) * 128 + (((cb) ^ (((tb) + ln15) & 7)) << 3)])
        #define LDB(m)  (*(const bh8*)&wcT[(m) * 16384 + (16 * w + ln15) * 128 + lq * 8 + 32 * ks])
            const bh8 a0 = LDA(0), a1 = LDA(16);
            accA = MFMA(a0, LDB(0), accA);
            accA = MFMA(a1, LDB(1), accA);
            const bh8 a2 = LDA(32), a3 = LDA(48), a4 = LDA(64), a5 = LDA(80);
            const bh8 bW1 = LDB(2), bWr = LDB(3);
            accB0 = MFMA(a2, bW1, accB0);
            accB0 = MFMA(a4, bWr, accB0);
            accB1 = MFMA(a3, bW1, accB1);
            accB1 = MFMA(a5, bWr, accB1);
            const bh8 bW2 = LDB(4);
            accC0 = MFMA(LDA(96),  bW2, accC0);
            accC1 = MFMA(LDA(112), bW2, accC1);
            accC2 = MFMA(LDA(128), bW2, accC2);
        #undef LDA
        #undef LDB
        }
        const int d = 16 * w + ln15;
        const float pb = proj_b[d];
        float* ob = out + (size_t)n0 * 1152 + d;
        #pragma unroll
        for (int r = 0; r < 4; ++r) {
            const int rt = lq * 4 + r;
            const int nd = rt & 7;
            float* obn = ob + (size_t)nd * 1152;
            if (rt < 8) obn[0] = accA[r] + pb;
            obn[(rt < 8 ? 1 : 2) * 128] = accB0[r];
            if (rt < 8) obn[3 * 128] = accB1[r];
            obn[(rt < 8 ? 4 : 5) * 128] = accC0[r];
            obn[(rt < 8 ? 6 : 7) * 128] = accC1[r];
            if (rt < 8) obn[8 * 128] = accC2[r];
        }
    }
}

extern "C" void kernel_launch(void* const* d_in, const int* in_sizes, int n_in,
                              void* d_out, int out_size, void* d_ws, size_t ws_size,
                              hipStream_t stream)
{
    const float* alpha        = (const float*)d_in[0];
    const float* value        = (const float*)d_in[1];
    const float* x_edge       = (const float*)d_in[2];
    const float* node_pos     = (const float*)d_in[3];
    const float* edge_dis     = (const float*)d_in[4];
    const float* exp_node_pos = (const float*)d_in[5];
    const float* rad_w1       = (const float*)d_in[6];
    const float* rad_b1       = (const float*)d_in[7];
    const float* ln_g         = (const float*)d_in[8];
    const float* ln_b         = (const float*)d_in[9];
    const float* rad_w2       = (const float*)d_in[10];
    const float* rad_b2       = (const float*)d_in[11];
    const float* tp_w_same    = (const float*)d_in[12];
    const float* tp_w_rv0     = (const float*)d_in[13];
    const float* tp_w_rdot    = (const float*)d_in[14];
    const float* proj_w       = (const float*)d_in[15];
    const float* proj_b       = (const float*)d_in[16];
    const int* outcell_index  = (const int*)d_in[17];
    const int* f_sparse_idx   = (const int*)d_in[18];
    float* out = (float*)d_out;
    unsigned short* ws = (unsigned short*)d_ws;

    const int N = in_sizes[0] / (16 * 8);   // 16000

    prep_kernel<<<656, 128, 0, stream>>>(rad_w1, rad_w2, tp_w_same, tp_w_rv0,
                                         tp_w_rdot, proj_w, ws);
    foa_main<<<N / NB, BLK, 0, stream>>>(alpha, value, x_edge, node_pos, edge_dis,
                                         exp_node_pos, rad_b1, ln_g, ln_b, rad_b2,
                                         proj_b, ws, outcell_index, f_sparse_idx, out);
}

// Round 5
// 225.169 us; speedup vs baseline: 3.1245x; 1.1666x over previous
//
#include <hip/hip_runtime.h>
#include <hip/hip_fp16.h>

typedef __attribute__((ext_vector_type(8))) short bh8;
typedef __attribute__((ext_vector_type(4))) float fv4;

#define NB 8
#define EB 128
#define BLK 512

#define MFMA(a, b, c) __builtin_amdgcn_mfma_f32_16x16x32_bf16((a), (b), (c), 0, 0, 0)

__device__ __forceinline__ unsigned short f2bf(float x) {
    unsigned int u = __float_as_uint(x);
    u += 0x7fffu + ((u >> 16) & 1u);
    return (unsigned short)(u >> 16);
}
__device__ __forceinline__ float bf2f(unsigned short h) {
    return __uint_as_float(((unsigned int)h) << 16);
}
// element index into a row-major [*][128] bf16 LDS tile, 8-elem XOR swizzle
__device__ __forceinline__ int swz(int row, int col) {
    return row * 128 + ((((col >> 3) ^ (row & 7)) << 3) | (col & 7));
}

// ws layout (ushort): [0,8192) w1T[128][64]; [8192,24576) w2T[128][128];
// [24576,106496) wcT[5][128][128]; [106496, +N*1152) vhf (fp16 value)
__global__ void prep_kernel(
    const float* __restrict__ rad_w1, const float* __restrict__ rad_w2,
    const float* __restrict__ tp_w_same, const float* __restrict__ tp_w_rv0,
    const float* __restrict__ tp_w_rdot, const float* __restrict__ proj_w,
    unsigned short* __restrict__ ws)
{
    unsigned short* w1T = ws;
    unsigned short* w2T = ws + 8192;
    unsigned short* wcT = ws + 24576;
    const int b = blockIdx.x, t = threadIdx.x;
    if (b < 640) {
        const int m = b >> 7, d = b & 127;
        const float* A; const float* B;
        if (m == 0)      { A = tp_w_same;         B = proj_w; }
        else if (m == 1) { A = tp_w_rdot;         B = proj_w; }
        else if (m == 2) { A = tp_w_same + 16384; B = proj_w + 16384; }
        else if (m == 3) { A = tp_w_rv0;          B = proj_w + 16384; }
        else             { A = tp_w_same + 32768; B = proj_w + 32768; }
        __shared__ float Bs[128];
        Bs[t] = B[t * 128 + d];
        __syncthreads();
        float acc = 0.f;
        const float* Ar = A + t * 128;
        #pragma unroll 4
        for (int x = 0; x < 128; ++x) acc = fmaf(Ar[x], Bs[x], acc);
        wcT[m * 16384 + d * 128 + t] = f2bf(acc);
    } else {
        const int bb = b - 640;
        #pragma unroll
        for (int i = 0; i < 12; ++i) {
            const int idx = bb * 1536 + i * 128 + t;
            if (idx < 8192) {
                const int j = idx >> 6, c = idx & 63;
                w1T[idx] = f2bf(rad_w1[c * 128 + j]);
            } else if (idx < 24576) {
                const int i2 = idx - 8192;
                const int j = i2 >> 7, c = i2 & 127;
                w2T[i2] = f2bf(rad_w2[c * 128 + j]);
            }
        }
    }
}

__global__ __launch_bounds__(256) void conv_value_kernel(
    const float* __restrict__ v, unsigned short* __restrict__ o, int n8)
{
    const int i = blockIdx.x * 256 + threadIdx.x;
    if (i >= n8) return;
    const float4 a = *(const float4*)(v + (size_t)i * 8);
    const float4 b = *(const float4*)(v + (size_t)i * 8 + 4);
    uint4 r;
    r.x = (unsigned int)__half_as_ushort(__float2half_rn(a.x)) |
          ((unsigned int)__half_as_ushort(__float2half_rn(a.y)) << 16);
    r.y = (unsigned int)__half_as_ushort(__float2half_rn(a.z)) |
          ((unsigned int)__half_as_ushort(__float2half_rn(a.w)) << 16);
    r.z = (unsigned int)__half_as_ushort(__float2half_rn(b.x)) |
          ((unsigned int)__half_as_ushort(__float2half_rn(b.y)) << 16);
    r.w = (unsigned int)__half_as_ushort(__float2half_rn(b.z)) |
          ((unsigned int)__half_as_ushort(__float2half_rn(b.w)) << 16);
    *(uint4*)(o + (size_t)i * 8) = r;
}

template <int VHALF>
__global__ __launch_bounds__(BLK, 4) void foa_main(
    const float* __restrict__ alpha,        // [N*K*8]
    const float* __restrict__ value,        // [N][9][128] fp32 (fallback)
    const float* __restrict__ x_edge,       // [N*K][64]
    const float* __restrict__ node_pos,     // [N][3]
    const float* __restrict__ edge_dis,     // [N*K]
    const float* __restrict__ exp_node_pos, // [M][3]
    const float* __restrict__ rad_b1, const float* __restrict__ ln_g,
    const float* __restrict__ ln_b, const float* __restrict__ rad_b2,
    const float* __restrict__ proj_b,
    const unsigned short* __restrict__ ws,
    const unsigned short* __restrict__ vhf, // fp16 value table
    const int* __restrict__ outcell_index,
    const int* __restrict__ f_sparse_idx,
    float* __restrict__ out)                // [N][9][128]
{
    // tpin (144 rows, 36 KB) aliases hbuf (128 rows): hbuf dead before tpin born
    __shared__ __align__(16) unsigned short s_un[18432];
    __shared__ __align__(16) unsigned short s_abuf[16384];
    __shared__ float s_alpha[1024];
    __shared__ float s_rE[EB][3];
    __shared__ float s_invd[EB];
    __shared__ int   s_gidx[EB];

    const unsigned short* w1T = ws;
    const unsigned short* w2T = ws + 8192;
    const unsigned short* wcT = ws + 24576;

    const int t = threadIdx.x;
    const int e0 = blockIdx.x * EB;
    const int n0 = blockIdx.x * NB;
    const int lane = t & 63, w = t >> 6;
    const int ln15 = lane & 15, lq = lane >> 4;

    // ---------- phase 0: per-edge metadata ----------
    if (t < EB) {
        const int eidx = f_sparse_idx[e0 + t];
        s_gidx[t] = outcell_index[eidx];
        const int nn = n0 + (t >> 4);
        s_rE[t][0] = node_pos[nn * 3 + 0] - exp_node_pos[(size_t)eidx * 3 + 0];
        s_rE[t][1] = node_pos[nn * 3 + 1] - exp_node_pos[(size_t)eidx * 3 + 1];
        s_rE[t][2] = node_pos[nn * 3 + 2] - exp_node_pos[(size_t)eidx * 3 + 2];
        s_invd[t] = 1.0f / (edge_dis[e0 + t] + 1e-8f);
    }
    s_alpha[t]       = alpha[(size_t)e0 * 8 + t];
    s_alpha[t + 512] = alpha[(size_t)e0 * 8 + 512 + t];

    unsigned short* hbuf = s_un;

    // ---------- phase 2: GEMM1 [128,64]@w1 -> LN -> SiLU -> hbuf (bf16) ----
    {
        bh8 af0, af1;
        {
            const float* xp = x_edge + ((size_t)(e0 + 16 * w + ln15)) * 64 + lq * 8;
            const float4 u0 = *(const float4*)(xp);
            const float4 u1 = *(const float4*)(xp + 4);
            const float4 u2 = *(const float4*)(xp + 32);
            const float4 u3 = *(const float4*)(xp + 36);
            af0[0] = (short)f2bf(u0.x); af0[1] = (short)f2bf(u0.y);
            af0[2] = (short)f2bf(u0.z); af0[3] = (short)f2bf(u0.w);
            af0[4] = (short)f2bf(u1.x); af0[5] = (short)f2bf(u1.y);
            af0[6] = (short)f2bf(u1.z); af0[7] = (short)f2bf(u1.w);
            af1[0] = (short)f2bf(u2.x); af1[1] = (short)f2bf(u2.y);
            af1[2] = (short)f2bf(u2.z); af1[3] = (short)f2bf(u2.w);
            af1[4] = (short)f2bf(u3.x); af1[5] = (short)f2bf(u3.y);
            af1[6] = (short)f2bf(u3.z); af1[7] = (short)f2bf(u3.w);
        }
        fv4 acc1[8];
        #pragma unroll
        for (int ct = 0; ct < 8; ++ct) { fv4 z = {0.f, 0.f, 0.f, 0.f}; acc1[ct] = z; }
        #pragma unroll
        for (int ct = 0; ct < 8; ++ct) {
            const bh8* bp = (const bh8*)&w1T[(16 * ct + ln15) * 64 + lq * 8];
            acc1[ct] = MFMA(af0, bp[0], acc1[ct]);
            acc1[ct] = MFMA(af1, bp[4], acc1[ct]);   // +32 elems = second k-tile
        }
        float b1v[8], gv[8], bvv[8];
        #pragma unroll
        for (int ct = 0; ct < 8; ++ct) {
            b1v[ct] = rad_b1[16 * ct + ln15];
            gv[ct]  = ln_g[16 * ct + ln15];
            bvv[ct] = ln_b[16 * ct + ln15];
        }
        #pragma unroll
        for (int r = 0; r < 4; ++r) {
            float vv[8], s = 0.f, s2 = 0.f;
            #pragma unroll
            for (int ct = 0; ct < 8; ++ct) {
                const float x = acc1[ct][r] + b1v[ct];
                vv[ct] = x; s += x; s2 += x * x;
            }
            s += __shfl_xor(s, 1);  s2 += __shfl_xor(s2, 1);
            s += __shfl_xor(s, 2);  s2 += __shfl_xor(s2, 2);
            s += __shfl_xor(s, 4);  s2 += __shfl_xor(s2, 4);
            s += __shfl_xor(s, 8);  s2 += __shfl_xor(s2, 8);
            const float mu = s * 0.0078125f;
            const float var = s2 * 0.0078125f - mu * mu;
            const float rstd = rsqrtf(var + 1e-5f);
            const int rowg = 16 * w + lq * 4 + r;
            #pragma unroll
            for (int ct = 0; ct < 8; ++ct) {
                float hh = (vv[ct] - mu) * rstd * gv[ct] + bvv[ct];
                hh = hh / (1.f + __expf(-hh));
                hbuf[swz(rowg, 16 * ct + ln15)] = f2bf(hh);
            }
        }
    }
    __syncthreads();

    // ---------- phase 3: GEMM2 [128,128]@w2 -> a -> s_abuf (bf16) ----------
    {
        fv4 acc2[8];
        #pragma unroll
        for (int ct = 0; ct < 8; ++ct) { fv4 z = {0.f, 0.f, 0.f, 0.f}; acc2[ct] = z; }
        #pragma unroll
        for (int ks = 0; ks < 4; ++ks) {
            const int arow = 16 * w + ln15;
            const int acb = (lq + 4 * ks) ^ (arow & 7);
            const bh8 a = *(const bh8*)&hbuf[arow * 128 + (acb << 3)];
            #pragma unroll
            for (int ct = 0; ct < 8; ++ct) {
                const bh8 b = *(const bh8*)&w2T[(16 * ct + ln15) * 128 + lq * 8 + 32 * ks];
                acc2[ct] = MFMA(a, b, acc2[ct]);
            }
        }
        #pragma unroll
        for (int ct = 0; ct < 8; ++ct) {
            const float b2 = rad_b2[16 * ct + ln15];
            #pragma unroll
            for (int r = 0; r < 4; ++r) {
                const int e = 16 * w + lq * 4 + r;
                const float aval = s_alpha[e * 8 + ct] * (acc2[ct][r] + b2) * s_invd[e];
                s_abuf[swz(e, 16 * ct + ln15)] = f2bf(aval);
            }
        }
    }
    __syncthreads();

    // ---------- phase 4: gather V, TP accumulate -> tpin (bf16, 144 rows) --
    // row map: nn=node 0..7: aV0->nn | ardot->16+nn | aV1..3->32+(l-1)*8+nn |
    //          arV0 x->64+x*8+nn | aV4..8->96+(l-4)*8+nn ; pad rows zeroed
    unsigned short* tpin = s_un;
    {
        const int padrows[5] = {8, 24, 56, 88, 136};
        #pragma unroll
        for (int g = 0; g < 5; ++g) {
            unsigned int* pz = (unsigned int*)&tpin[padrows[g] * 128];
            pz[t] = 0u;   // 8 rows * 128 bf16 = 512 uints, one per thread
        }
    }
    {
        const int c = t & 127;
        const int ng = t >> 7;
        #pragma unroll
        for (int hh = 0; hh < 2; ++hh) {
            const int nn = 2 * ng + hh;
            float aV0 = 0.f, aV1 = 0.f, aV2 = 0.f, aV3 = 0.f, aV4 = 0.f;
            float aV5 = 0.f, aV6 = 0.f, aV7 = 0.f, aV8 = 0.f;
            float ar0 = 0.f, ar1 = 0.f, ar2 = 0.f, ard = 0.f;
            #pragma unroll 4
            for (int k = 0; k < 16; ++k) {
                const int e = nn * 16 + k;
                const float av = bf2f(s_abuf[swz(e, c)]);
                float v0, v1, v2, v3, v4, v5, v6, v7, v8;
                if constexpr (VHALF) {
                    const __half* vp = (const __half*)vhf + (size_t)s_gidx[e] * 1152 + c;
                    v0 = __half2float(vp[0]);    v1 = __half2float(vp[128]);
                    v2 = __half2float(vp[256]);  v3 = __half2float(vp[384]);
                    v4 = __half2float(vp[512]);  v5 = __half2float(vp[640]);
                    v6 = __half2float(vp[768]);  v7 = __half2float(vp[896]);
                    v8 = __half2float(vp[1024]);
                } else {
                    const float* vp = value + (size_t)s_gidx[e] * 1152 + c;
                    v0 = vp[0];    v1 = vp[128];  v2 = vp[256];
                    v3 = vp[384];  v4 = vp[512];  v5 = vp[640];
                    v6 = vp[768];  v7 = vp[896];  v8 = vp[1024];
                }
                aV0 = fmaf(av, v0, aV0); aV1 = fmaf(av, v1, aV1);
                aV2 = fmaf(av, v2, aV2); aV3 = fmaf(av, v3, aV3);
                aV4 = fmaf(av, v4, aV4); aV5 = fmaf(av, v5, aV5);
                aV6 = fmaf(av, v6, aV6); aV7 = fmaf(av, v7, aV7);
                aV8 = fmaf(av, v8, aV8);
                const float r0 = s_rE[e][0], r1 = s_rE[e][1], r2 = s_rE[e][2];
                const float w0 = av * v0;
                ar0 = fmaf(r0, w0, ar0);
                ar1 = fmaf(r1, w0, ar1);
                ar2 = fmaf(r2, w0, ar2);
                ard = fmaf(av, fmaf(r0, v1, fmaf(r1, v2, r2 * v3)), ard);
            }
            tpin[swz(nn, c)]       = f2bf(aV0);
            tpin[swz(16 + nn, c)]  = f2bf(ard);
            tpin[swz(32 + nn, c)]  = f2bf(aV1);
            tpin[swz(40 + nn, c)]  = f2bf(aV2);
            tpin[swz(48 + nn, c)]  = f2bf(aV3);
            tpin[swz(64 + nn, c)]  = f2bf(ar0);
            tpin[swz(72 + nn, c)]  = f2bf(ar1);
            tpin[swz(80 + nn, c)]  = f2bf(ar2);
            tpin[swz(96 + nn, c)]  = f2bf(aV4);
            tpin[swz(104 + nn, c)] = f2bf(aV5);
            tpin[swz(112 + nn, c)] = f2bf(aV6);
            tpin[swz(120 + nn, c)] = f2bf(aV7);
            tpin[swz(128 + nn, c)] = f2bf(aV8);
        }
    }
    __syncthreads();

    // ---------- phase 5: MFMA projection through combined weights ----------
    {
        fv4 accA, accB0, accB1, accC0, accC1, accC2;
        { fv4 z = {0.f,0.f,0.f,0.f}; accA=z; accB0=z; accB1=z; accC0=z; accC1=z; accC2=z; }
        #pragma unroll
        for (int ks = 0; ks < 4; ++ks) {
            const int cb = lq + 4 * ks;
        #define LDA(tb) (*(const bh8*)&tpin[((tb) + ln15) * 128 + (((cb) ^ (((tb) + ln15) & 7)) << 3)])
        #define LDB(m)  (*(const bh8*)&wcT[(m) * 16384 + (16 * w + ln15) * 128 + lq * 8 + 32 * ks])
            const bh8 a0 = LDA(0), a1 = LDA(16);
            accA = MFMA(a0, LDB(0), accA);
            accA = MFMA(a1, LDB(1), accA);
            const bh8 a2 = LDA(32), a3 = LDA(48), a4 = LDA(64), a5 = LDA(80);
            const bh8 bW1 = LDB(2), bWr = LDB(3);
            accB0 = MFMA(a2, bW1, accB0);
            accB0 = MFMA(a4, bWr, accB0);
            accB1 = MFMA(a3, bW1, accB1);
            accB1 = MFMA(a5, bWr, accB1);
            const bh8 bW2 = LDB(4);
            accC0 = MFMA(LDA(96),  bW2, accC0);
            accC1 = MFMA(LDA(112), bW2, accC1);
            accC2 = MFMA(LDA(128), bW2, accC2);
        #undef LDA
        #undef LDB
        }
        const int d = 16 * w + ln15;
        const float pb = proj_b[d];
        float* ob = out + (size_t)n0 * 1152 + d;
        #pragma unroll
        for (int r = 0; r < 4; ++r) {
            const int rt = lq * 4 + r;
            const int nd = rt & 7;
            float* obn = ob + (size_t)nd * 1152;
            if (rt < 8) obn[0] = accA[r] + pb;
            obn[(rt < 8 ? 1 : 2) * 128] = accB0[r];
            if (rt < 8) obn[3 * 128] = accB1[r];
            obn[(rt < 8 ? 4 : 5) * 128] = accC0[r];
            obn[(rt < 8 ? 6 : 7) * 128] = accC1[r];
            if (rt < 8) obn[8 * 128] = accC2[r];
        }
    }
}

extern "C" void kernel_launch(void* const* d_in, const int* in_sizes, int n_in,
                              void* d_out, int out_size, void* d_ws, size_t ws_size,
                              hipStream_t stream)
{
    const float* alpha        = (const float*)d_in[0];
    const float* value        = (const float*)d_in[1];
    const float* x_edge       = (const float*)d_in[2];
    const float* node_pos     = (const float*)d_in[3];
    const float* edge_dis     = (const float*)d_in[4];
    const float* exp_node_pos = (const float*)d_in[5];
    const float* rad_w1       = (const float*)d_in[6];
    const float* rad_b1       = (const float*)d_in[7];
    const float* ln_g         = (const float*)d_in[8];
    const float* ln_b         = (const float*)d_in[9];
    const float* rad_w2       = (const float*)d_in[10];
    const float* rad_b2       = (const float*)d_in[11];
    const float* tp_w_same    = (const float*)d_in[12];
    const float* tp_w_rv0     = (const float*)d_in[13];
    const float* tp_w_rdot    = (const float*)d_in[14];
    const float* proj_w       = (const float*)d_in[15];
    const float* proj_b       = (const float*)d_in[16];
    const int* outcell_index  = (const int*)d_in[17];
    const int* f_sparse_idx   = (const int*)d_in[18];
    float* out = (float*)d_out;
    unsigned short* ws = (unsigned short*)d_ws;

    const int N = in_sizes[0] / (16 * 8);   // 16000
    const int vElems = in_sizes[1];         // N*1152

    prep_kernel<<<656, 128, 0, stream>>>(rad_w1, rad_w2, tp_w_same, tp_w_rv0,
                                         tp_w_rdot, proj_w, ws);

    const size_t need = ((size_t)106496 + (size_t)vElems) * 2;
    if (ws_size >= need) {
        unsigned short* vhf = ws + 106496;
        const int n8 = vElems / 8;
        conv_value_kernel<<<(n8 + 255) / 256, 256, 0, stream>>>(value, vhf, n8);
        foa_main<1><<<N / NB, BLK, 0, stream>>>(alpha, value, x_edge, node_pos, edge_dis,
                                                exp_node_pos, rad_b1, ln_g, ln_b, rad_b2,
                                                proj_b, ws, vhf, outcell_index,
                                                f_sparse_idx, out);
    } else {
        foa_main<0><<<N / NB, BLK, 0, stream>>>(alpha, value, x_edge, node_pos, edge_dis,
                                                exp_node_pos, rad_b1, ln_g, ln_b, rad_b2,
                                                proj_b, ws, ws, outcell_index,
                                                f_sparse_idx, out);
    }
}